// Round 5
// baseline (481.510 us; speedup 1.0000x reference)
//
#include <hip/hip_runtime.h>
#include <hip/hip_bf16.h>
#include <hip/hip_cooperative_groups.h>

namespace cg = cooperative_groups;

// ---------------------------------------------------------------------------
// GAT 2-layer forward on MI355X (gfx950).
// R4: dispatch-count attack. 13 -> 5 dispatches:
//   (1) cooperative CSR build (zero+count+scan+scatter, grid.sync between)
//   (2) gemm1 + fused att-logit epilogue   (3) aggregate1 (R2-proven form)
//   (4) gemm2 + fused att-logit epilogue   (5) aggregate2 (R2-proven form)
// fp16 intermediates, MFMA f16 GEMMs, softmax shift-invariance (no max pass),
// end-normalization (no separate denom pass).
// ---------------------------------------------------------------------------

typedef _Float16 half8v __attribute__((ext_vector_type(8)));
typedef _Float16 half4v __attribute__((ext_vector_type(4)));
typedef _Float16 half2v __attribute__((ext_vector_type(2)));
typedef float f32x4 __attribute__((ext_vector_type(4)));

// --- MFMA GEMM + fused attention logits ------------------------------------
// C[M, H*128](f16) = A[M,K] @ B[H*128, K]^T ; additionally
// a_s[m,by] = dot(C_row_head, att_s[by]); a_d likewise — computed from fp32
// accumulators in the epilogue (2 KB LDS cross-wave combine, no atomics).
// 128x128 tile, BK=32, 256 threads = 4 waves (2x2); grid.y = H (head).

template <typename TA, int H>
__global__ __launch_bounds__(256) void gemm_att_kernel(
    const TA* __restrict__ A,        // [M,K] row-major (float or _Float16)
    const float* __restrict__ B,     // [H*128, K] row-major fp32 weights
    _Float16* __restrict__ C,        // [M, H*128] fp16 out
    const float* __restrict__ att_s, // [H*128]
    const float* __restrict__ att_d, // [H*128]
    float* __restrict__ a_s,         // [M*H]
    float* __restrict__ a_d,         // [M*H]
    int M, int K)
{
    constexpr int BM = 128, BK = 32, LDA = 40;   // 40 f16 = 80 B = 5*16 B
    constexpr int NCOL = H * 128;
    __shared__ _Float16 Ah[BM * LDA];
    __shared__ _Float16 Bh[BM * LDA];
    __shared__ float red[2][2][64][2];           // [wm][wn][row][s|d]

    const int tid = threadIdx.x;
    const int m0 = blockIdx.x * BM;
    const int by = blockIdx.y;                   // head
    const int n0 = by * 128;
    const int w  = tid >> 6;
    const int l  = tid & 63;
    const int wm = (w >> 1) * 64;
    const int wn = (w & 1) * 64;
    const int lr = l & 15;
    const int lq = l >> 4;

    f32x4 acc[4][4] = {};

    for (int k0 = 0; k0 < K; k0 += BK) {
        if constexpr (__is_same(TA, float)) {
#pragma unroll
            for (int it = 0; it < 4; ++it) {
                const int row = (tid >> 3) + it * 32;
                const int gm  = min(m0 + row, M - 1);
                const int c4  = (tid & 7) * 4;
                float4 v = *reinterpret_cast<const float4*>(A + (long)gm * K + k0 + c4);
                half4v o = { (_Float16)v.x, (_Float16)v.y, (_Float16)v.z, (_Float16)v.w };
                *reinterpret_cast<half4v*>(&Ah[row * LDA + c4]) = o;
            }
        } else {
#pragma unroll
            for (int it = 0; it < 2; ++it) {
                const int row = (tid >> 2) + it * 64;
                const int gm  = min(m0 + row, M - 1);
                const int c8  = (tid & 3) * 8;
                float4 v = *reinterpret_cast<const float4*>((const char*)A + ((long)gm * K + k0 + c8) * 2);
                *reinterpret_cast<float4*>(&Ah[row * LDA + c8]) = v;
            }
        }
#pragma unroll
        for (int it = 0; it < 4; ++it) {
            const int row = (tid >> 3) + it * 32;
            const int c4  = (tid & 7) * 4;
            float4 v = *reinterpret_cast<const float4*>(B + (long)(n0 + row) * K + k0 + c4);
            half4v o = { (_Float16)v.x, (_Float16)v.y, (_Float16)v.z, (_Float16)v.w };
            *reinterpret_cast<half4v*>(&Bh[row * LDA + c4]) = o;
        }
        __syncthreads();

        half8v af[4], bf[4];
#pragma unroll
        for (int i = 0; i < 4; ++i)
            af[i] = *reinterpret_cast<const half8v*>(&Ah[(wm + i * 16 + lr) * LDA + lq * 8]);
#pragma unroll
        for (int j = 0; j < 4; ++j)
            bf[j] = *reinterpret_cast<const half8v*>(&Bh[(wn + j * 16 + lr) * LDA + lq * 8]);
#pragma unroll
        for (int i = 0; i < 4; ++i)
#pragma unroll
            for (int j = 0; j < 4; ++j)
                acc[i][j] = __builtin_amdgcn_mfma_f32_16x16x32_f16(af[i], bf[j], acc[i][j], 0, 0, 0);
        __syncthreads();
    }

    // ---- store C ----
#pragma unroll
    for (int i = 0; i < 4; ++i) {
        const int gm_base = m0 + wm + i * 16 + lq * 4;
#pragma unroll
        for (int r = 0; r < 4; ++r) {
            const int gm = gm_base + r;
            if (gm < M) {
#pragma unroll
                for (int j = 0; j < 4; ++j)
                    C[(long)gm * NCOL + n0 + wn + j * 16 + lr] = (_Float16)acc[i][j][r];
            }
        }
    }

    // ---- fused attention logits ----
    float asv[4], adv[4];
#pragma unroll
    for (int j = 0; j < 4; ++j) {
        asv[j] = att_s[n0 + wn + j * 16 + lr];
        adv[j] = att_d[n0 + wn + j * 16 + lr];
    }
    float ps[4][4] = {}, pd[4][4] = {};
#pragma unroll
    for (int i = 0; i < 4; ++i)
#pragma unroll
        for (int j = 0; j < 4; ++j)
#pragma unroll
            for (int r = 0; r < 4; ++r) {
                ps[i][r] += acc[i][j][r] * asv[j];
                pd[i][r] += acc[i][j][r] * adv[j];
            }
    // reduce across the 16 lr-lanes (lanes of one quad: low 4 lane bits)
#pragma unroll
    for (int o = 1; o < 16; o <<= 1)
#pragma unroll
        for (int i = 0; i < 4; ++i)
#pragma unroll
            for (int r = 0; r < 4; ++r) {
                ps[i][r] += __shfl_xor(ps[i][r], o, 64);
                pd[i][r] += __shfl_xor(pd[i][r], o, 64);
            }
    if (lr == 0) {
#pragma unroll
        for (int i = 0; i < 4; ++i)
#pragma unroll
            for (int r = 0; r < 4; ++r) {
                const int row = i * 16 + lq * 4 + r;
                red[wm >> 6][wn >> 6][row][0] = ps[i][r];
                red[wm >> 6][wn >> 6][row][1] = pd[i][r];
            }
    }
    __syncthreads();
    if (wn == 0) {                       // waves 0 and 2 cover wm = 0, 64
        const int row = l;
        const int gm = m0 + wm + row;
        if (gm < M) {
            const int wi = wm >> 6;
            a_s[(long)gm * H + by] = red[wi][0][row][0] + red[wi][1][row][0];
            a_d[(long)gm * H + by] = red[wi][0][row][1] + red[wi][1][row][1];
        }
    }
}

// --- cooperative CSR build (one dispatch) ----------------------------------
// stages: zero deg -> count -> block scans -> total scan -> finalize -> scatter

__global__ __launch_bounds__(256) void csr_build_kernel(
    const int* __restrict__ src, const int* __restrict__ dst,
    int* __restrict__ deg, int* __restrict__ pre,
    int* __restrict__ blk, int* __restrict__ blk_off,
    int* __restrict__ csr_off, int* __restrict__ cursor,
    int* __restrict__ csr_src, int E, int N)
{
    cg::grid_group grid = cg::this_grid();
    const int tid  = blockIdx.x * blockDim.x + threadIdx.x;
    const int nthr = gridDim.x * blockDim.x;
    const int t    = threadIdx.x;

    // stage 0: zero degrees
    for (int i = tid; i < N; i += nthr) deg[i] = 0;
    grid.sync();

    // stage 1: count (int4 edge reads)
    const int nq = (E + 3) / 4;
    for (int q = tid; q < nq; q += nthr) {
        const int e4 = q * 4;
        if (e4 + 3 < E) {
            const int4 d = *reinterpret_cast<const int4*>(dst + e4);
            atomicAdd(&deg[d.x], 1);
            atomicAdd(&deg[d.y], 1);
            atomicAdd(&deg[d.z], 1);
            atomicAdd(&deg[d.w], 1);
        } else {
            for (int k = e4; k < E; ++k) atomicAdd(&deg[dst[k]], 1);
        }
    }
    grid.sync();

    // stage 2a: per-virtual-block scans of (deg[i]+1), 1024 elems each
    __shared__ int s[256];
    const int nvb = (N + 1023) / 1024;
    for (int vb = blockIdx.x; vb < nvb; vb += gridDim.x) {
        const int base = vb * 1024 + t * 4;
        int4 d = make_int4(-1, -1, -1, -1);   // +1 -> 0 contribution OOB
        if (base + 3 < N) d = *reinterpret_cast<const int4*>(deg + base);
        else {
            if (base + 0 < N) d.x = deg[base + 0];
            if (base + 1 < N) d.y = deg[base + 1];
            if (base + 2 < N) d.z = deg[base + 2];
            if (base + 3 < N) d.w = deg[base + 3];
        }
        const int v0 = d.x + 1, v1 = d.y + 1, v2 = d.z + 1, v3 = d.w + 1;
        s[t] = v0 + v1 + v2 + v3;
        __syncthreads();
#pragma unroll
        for (int o = 1; o < 256; o <<= 1) {
            int val = 0;
            if (t >= o) val = s[t - o];
            __syncthreads();
            s[t] += val;
            __syncthreads();
        }
        int run = (t == 0) ? 0 : s[t - 1];
        int4 o4;
        o4.x = run; run += v0;
        o4.y = run; run += v1;
        o4.z = run; run += v2;
        o4.w = run; run += v3;
        if (base + 3 < N) *reinterpret_cast<int4*>(pre + base) = o4;
        else {
            if (base + 0 < N) pre[base + 0] = o4.x;
            if (base + 1 < N) pre[base + 1] = o4.y;
            if (base + 2 < N) pre[base + 2] = o4.z;
            if (base + 3 < N) pre[base + 3] = o4.w;
        }
        if (t == 255) blk[vb] = s[255];
        __syncthreads();
    }
    grid.sync();

    // stage 2b: one wave scans virtual-block totals
    if (blockIdx.x == 0 && t < 64) {
        const int self = (t < nvb) ? blk[t] : 0;
        int v = self;
#pragma unroll
        for (int o = 1; o < 64; o <<= 1) {
            int u = __shfl_up(v, o, 64);
            if (t >= o) v += u;
        }
        if (t < nvb) blk_off[t] = v - self;
        if (t == nvb - 1) csr_off[N] = v;
    }
    grid.sync();

    // stage 2c: finalize csr_off + cursor
    for (int vb = blockIdx.x; vb < nvb; vb += gridDim.x) {
        const int base = vb * 1024 + t * 4;
        const int add = blk_off[vb];
        if (base + 3 < N) {
            int4 p = *reinterpret_cast<const int4*>(pre + base);
            p.x += add; p.y += add; p.z += add; p.w += add;
            *reinterpret_cast<int4*>(csr_off + base) = p;
            *reinterpret_cast<int4*>(cursor + base) = p;
        } else {
#pragma unroll
            for (int k = 0; k < 4; ++k)
                if (base + k < N) {
                    const int v = pre[base + k] + add;
                    csr_off[base + k] = v;
                    cursor[base + k] = v;
                }
        }
    }
    grid.sync();

    // stage 3: scatter edges + self loops
    const int W = nq + N;
    for (int wi = tid; wi < W; wi += nthr) {
        if (wi < nq) {
            const int e4 = wi * 4;
            if (e4 + 3 < E) {
                const int4 sv = *reinterpret_cast<const int4*>(src + e4);
                const int4 dv = *reinterpret_cast<const int4*>(dst + e4);
                csr_src[atomicAdd(&cursor[dv.x], 1)] = sv.x;
                csr_src[atomicAdd(&cursor[dv.y], 1)] = sv.y;
                csr_src[atomicAdd(&cursor[dv.z], 1)] = sv.z;
                csr_src[atomicAdd(&cursor[dv.w], 1)] = sv.w;
            } else {
                for (int k = e4; k < E; ++k)
                    csr_src[atomicAdd(&cursor[dst[k]], 1)] = src[k];
            }
        } else {
            const int nn = wi - nq;
            csr_src[atomicAdd(&cursor[nn], 1)] = nn;
        }
    }
}

// --- pull-based aggregation (R2-proven form) -------------------------------
// out[d,c] = (sum_e w * h[s_e,c]) / (sum_e w) [+bias][relu];  one 64-thread
// block per dst; weights + src idx tiled through LDS.

#define AGG_TILE 64

template <int H, int C, int VPT, bool RELU, typename TOUT>
__global__ __launch_bounds__(H * C / VPT) void aggregate_kernel(
    const int* __restrict__ csr_off,
    const int* __restrict__ csr_src,
    const _Float16* __restrict__ h,  // [N, H*C] fp16
    const float* __restrict__ a_s,   // [N, H]
    const float* __restrict__ a_d,   // [N, H]
    const float* __restrict__ bias,  // [H*C]
    TOUT* __restrict__ out)          // [N, H*C]
{
    const int d   = blockIdx.x;
    const int t   = threadIdx.x;
    const int col = t * VPT;
    const int hh  = col / C;

    __shared__ int   s_src[AGG_TILE];
    __shared__ float s_w[AGG_TILE][H];

    const int beg = csr_off[d];
    const int end = csr_off[d + 1];

    float acc[VPT] = {};
    float wsum = 0.f;

    for (int base = beg; base < end; base += AGG_TILE) {
        const int len = min(AGG_TILE, end - base);
        if (t < len) {
            const int s = csr_src[base + t];
            s_src[t] = s;
#pragma unroll
            for (int h2 = 0; h2 < H; ++h2) {
                float logit = a_s[s * H + h2] + a_d[d * H + h2];
                logit = logit > 0.f ? logit : 0.2f * logit;
                s_w[t][h2] = __expf(logit);
            }
        }
        __syncthreads();
#pragma unroll 4
        for (int j = 0; j < len; ++j) {
            const float w = s_w[j][hh];
            const int   s = s_src[j];
            if constexpr (VPT == 4) {
                half4v hv = *reinterpret_cast<const half4v*>(h + (long)s * (H * C) + col);
                acc[0] += w * (float)hv.x;
                acc[1] += w * (float)hv.y;
                acc[2] += w * (float)hv.z;
                acc[3] += w * (float)hv.w;
            } else {
                half2v hv = *reinterpret_cast<const half2v*>(h + (long)s * (H * C) + col);
                acc[0] += w * (float)hv.x;
                acc[1] += w * (float)hv.y;
            }
            wsum += w;
        }
        __syncthreads();
    }

    const float inv = 1.f / wsum;
    float r[VPT];
#pragma unroll
    for (int k = 0; k < VPT; ++k) {
        r[k] = acc[k] * inv + bias[col + k];
        if (RELU) r[k] = r[k] > 0.f ? r[k] : 0.f;
    }
    if constexpr (__is_same(TOUT, _Float16)) {
#pragma unroll
        for (int k = 0; k < VPT; ++k)
            out[(long)d * (H * C) + col + k] = (_Float16)r[k];
    } else {
#pragma unroll
        for (int k = 0; k < VPT; ++k)
            out[(long)d * (H * C) + col + k] = r[k];
    }
}

// ---------------------------------------------------------------------------

extern "C" void kernel_launch(void* const* d_in, const int* in_sizes, int n_in,
                              void* d_out, int out_size, void* d_ws, size_t ws_size,
                              hipStream_t stream)
{
    const float* x    = (const float*)d_in[0];
    const int*   eidx = (const int*)d_in[1];
    const float* W1   = (const float*)d_in[2];
    const float* as1  = (const float*)d_in[3];
    const float* ad1  = (const float*)d_in[4];
    const float* b1   = (const float*)d_in[5];
    const float* W2   = (const float*)d_in[6];
    const float* as2  = (const float*)d_in[7];
    const float* ad2  = (const float*)d_in[8];
    const float* b2   = (const float*)d_in[9];
    float* out = (float*)d_out;

    const int IN_FEATS = 256;
    int N = in_sizes[0] / IN_FEATS;    // 50000
    int E = in_sizes[1] / 2;           // 800000

    const int* esrc = eidx;
    const int* edst = eidx + E;

    size_t off = 0;
    auto alloc = [&](size_t bytes) -> void* {
        void* p = (char*)d_ws + off;
        off += (bytes + 255) & ~(size_t)255;
        return p;
    };
    _Float16* h1h   = (_Float16*)alloc((size_t)N * 256 * 2);
    _Float16* o1h   = (_Float16*)alloc((size_t)N * 256 * 2);
    _Float16* h2h   = (_Float16*)alloc((size_t)N * 128 * 2);
    float* a1s      = (float*)alloc((size_t)N * 2 * 4);
    float* a1d      = (float*)alloc((size_t)N * 2 * 4);
    float* a2s      = (float*)alloc((size_t)N * 4);
    float* a2d      = (float*)alloc((size_t)N * 4);
    int*   deg      = (int*)alloc((size_t)N * 4);
    int*   pre      = (int*)alloc((size_t)N * 4);
    int*   cursor   = (int*)alloc((size_t)N * 4);
    int*   csr_off  = (int*)alloc((size_t)(N + 1) * 4);
    int*   csr_src  = (int*)alloc((size_t)(E + N) * 4);
    int*   blk      = (int*)alloc(64 * 4);
    int*   blk_off  = (int*)alloc(64 * 4);

    // --- (1) CSR build: single cooperative dispatch ---
    {
        void* args[] = { (void*)&esrc, (void*)&edst, (void*)&deg, (void*)&pre,
                         (void*)&blk, (void*)&blk_off, (void*)&csr_off,
                         (void*)&cursor, (void*)&csr_src, (void*)&E, (void*)&N };
        hipLaunchCooperativeKernel((void*)csr_build_kernel, dim3(256), dim3(256),
                                   args, 0, stream);
    }

    // --- (2) layer-1 GEMM + fused att logits ---
    {
        dim3 grid((N + 127) / 128, 2);
        gemm_att_kernel<float, 2><<<grid, 256, 0, stream>>>(
            x, W1, h1h, as1, ad1, a1s, a1d, N, 256);
    }
    // --- (3) layer-1 aggregate ---
    aggregate_kernel<2, 128, 4, true, _Float16><<<N, 64, 0, stream>>>(
        csr_off, csr_src, h1h, a1s, a1d, b1, o1h);

    // --- (4) layer-2 GEMM + fused att logits ---
    {
        dim3 grid((N + 127) / 128, 1);
        gemm_att_kernel<_Float16, 1><<<grid, 256, 0, stream>>>(
            o1h, W2, h2h, as2, ad2, a2s, a2d, N, 256);
    }
    // --- (5) layer-2 aggregate ---
    aggregate_kernel<1, 128, 2, false, float><<<N, 64, 0, stream>>>(
        csr_off, csr_src, h2h, a2s, a2d, b2, out);
}

// Round 6
// 337.929 us; speedup vs baseline: 1.4249x; 1.4249x over previous
//
#include <hip/hip_runtime.h>
#include <hip/hip_bf16.h>

// ---------------------------------------------------------------------------
// GAT 2-layer forward on MI355X (gfx950).
// R5: R2-proven multi-kernel CSR build restored (coop single-dispatch build
//     was a 221us disaster: co-residency caps grid at 256 blocks -> atomics
//     starved). total_scan merged into finalize (one less dispatch).
//     Fused gemm+att-logit epilogue kept from R4. R2-form aggregates kept.
// 9 dispatches total. fp16 intermediates, MFMA f16 GEMMs, softmax
// shift-invariance (no max pass), end-normalization (no denom pass).
// ---------------------------------------------------------------------------

typedef _Float16 half8v __attribute__((ext_vector_type(8)));
typedef _Float16 half4v __attribute__((ext_vector_type(4)));
typedef _Float16 half2v __attribute__((ext_vector_type(2)));
typedef float f32x4 __attribute__((ext_vector_type(4)));

// --- MFMA GEMM + fused attention logits ------------------------------------
// C[M, H*128](f16) = A[M,K] @ B[H*128, K]^T ; additionally
// a_s[m,by] = dot(C_row_head, att_s[by]); a_d likewise — from fp32
// accumulators in the epilogue. 128x128 tile, BK=32, 4 waves; grid.y = head.

template <typename TA, int H>
__global__ __launch_bounds__(256) void gemm_att_kernel(
    const TA* __restrict__ A,        // [M,K] row-major (float or _Float16)
    const float* __restrict__ B,     // [H*128, K] row-major fp32 weights
    _Float16* __restrict__ C,        // [M, H*128] fp16 out
    const float* __restrict__ att_s, // [H*128]
    const float* __restrict__ att_d, // [H*128]
    float* __restrict__ a_s,         // [M*H]
    float* __restrict__ a_d,         // [M*H]
    int M, int K)
{
    constexpr int BM = 128, BK = 32, LDA = 40;   // 40 f16 = 80 B = 5*16 B
    constexpr int NCOL = H * 128;
    __shared__ _Float16 Ah[BM * LDA];
    __shared__ _Float16 Bh[BM * LDA];
    __shared__ float red[2][2][64][2];           // [wm][wn][row][s|d]

    const int tid = threadIdx.x;
    const int m0 = blockIdx.x * BM;
    const int by = blockIdx.y;                   // head
    const int n0 = by * 128;
    const int w  = tid >> 6;
    const int l  = tid & 63;
    const int wm = (w >> 1) * 64;
    const int wn = (w & 1) * 64;
    const int lr = l & 15;
    const int lq = l >> 4;

    f32x4 acc[4][4] = {};

    for (int k0 = 0; k0 < K; k0 += BK) {
        if constexpr (__is_same(TA, float)) {
#pragma unroll
            for (int it = 0; it < 4; ++it) {
                const int row = (tid >> 3) + it * 32;
                const int gm  = min(m0 + row, M - 1);
                const int c4  = (tid & 7) * 4;
                float4 v = *reinterpret_cast<const float4*>(A + (long)gm * K + k0 + c4);
                half4v o = { (_Float16)v.x, (_Float16)v.y, (_Float16)v.z, (_Float16)v.w };
                *reinterpret_cast<half4v*>(&Ah[row * LDA + c4]) = o;
            }
        } else {
#pragma unroll
            for (int it = 0; it < 2; ++it) {
                const int row = (tid >> 2) + it * 64;
                const int gm  = min(m0 + row, M - 1);
                const int c8  = (tid & 3) * 8;
                float4 v = *reinterpret_cast<const float4*>((const char*)A + ((long)gm * K + k0 + c8) * 2);
                *reinterpret_cast<float4*>(&Ah[row * LDA + c8]) = v;
            }
        }
#pragma unroll
        for (int it = 0; it < 4; ++it) {
            const int row = (tid >> 3) + it * 32;
            const int c4  = (tid & 7) * 4;
            float4 v = *reinterpret_cast<const float4*>(B + (long)(n0 + row) * K + k0 + c4);
            half4v o = { (_Float16)v.x, (_Float16)v.y, (_Float16)v.z, (_Float16)v.w };
            *reinterpret_cast<half4v*>(&Bh[row * LDA + c4]) = o;
        }
        __syncthreads();

        half8v af[4], bf[4];
#pragma unroll
        for (int i = 0; i < 4; ++i)
            af[i] = *reinterpret_cast<const half8v*>(&Ah[(wm + i * 16 + lr) * LDA + lq * 8]);
#pragma unroll
        for (int j = 0; j < 4; ++j)
            bf[j] = *reinterpret_cast<const half8v*>(&Bh[(wn + j * 16 + lr) * LDA + lq * 8]);
#pragma unroll
        for (int i = 0; i < 4; ++i)
#pragma unroll
            for (int j = 0; j < 4; ++j)
                acc[i][j] = __builtin_amdgcn_mfma_f32_16x16x32_f16(af[i], bf[j], acc[i][j], 0, 0, 0);
        __syncthreads();
    }

    // ---- store C ----
#pragma unroll
    for (int i = 0; i < 4; ++i) {
        const int gm_base = m0 + wm + i * 16 + lq * 4;
#pragma unroll
        for (int r = 0; r < 4; ++r) {
            const int gm = gm_base + r;
            if (gm < M) {
#pragma unroll
                for (int j = 0; j < 4; ++j)
                    C[(long)gm * NCOL + n0 + wn + j * 16 + lr] = (_Float16)acc[i][j][r];
            }
        }
    }

    // ---- fused attention logits ----
    float asv[4], adv[4];
#pragma unroll
    for (int j = 0; j < 4; ++j) {
        asv[j] = att_s[n0 + wn + j * 16 + lr];
        adv[j] = att_d[n0 + wn + j * 16 + lr];
    }
    float ps[4][4] = {}, pd[4][4] = {};
#pragma unroll
    for (int i = 0; i < 4; ++i)
#pragma unroll
        for (int j = 0; j < 4; ++j)
#pragma unroll
            for (int r = 0; r < 4; ++r) {
                ps[i][r] += acc[i][j][r] * asv[j];
                pd[i][r] += acc[i][j][r] * adv[j];
            }
#pragma unroll
    for (int o = 1; o < 16; o <<= 1)
#pragma unroll
        for (int i = 0; i < 4; ++i)
#pragma unroll
            for (int r = 0; r < 4; ++r) {
                ps[i][r] += __shfl_xor(ps[i][r], o, 64);
                pd[i][r] += __shfl_xor(pd[i][r], o, 64);
            }
    if (lr == 0) {
#pragma unroll
        for (int i = 0; i < 4; ++i)
#pragma unroll
            for (int r = 0; r < 4; ++r) {
                const int row = i * 16 + lq * 4 + r;
                red[wm >> 6][wn >> 6][row][0] = ps[i][r];
                red[wm >> 6][wn >> 6][row][1] = pd[i][r];
            }
    }
    __syncthreads();
    if (wn == 0) {                       // waves 0 and 2 cover wm = 0, 64
        const int row = l;
        const int gm = m0 + wm + row;
        if (gm < M) {
            const int wi = wm >> 6;
            a_s[(long)gm * H + by] = red[wi][0][row][0] + red[wi][1][row][0];
            a_d[(long)gm * H + by] = red[wi][0][row][1] + red[wi][1][row][1];
        }
    }
}

// --- CSR build (multi-kernel, R2-proven) -----------------------------------

__global__ void count_kernel(const int* __restrict__ dst, int* __restrict__ deg, int E)
{
    const int tid = blockIdx.x * blockDim.x + threadIdx.x;
    const int e4 = tid * 4;
    if (e4 + 3 < E) {
        const int4 d = *reinterpret_cast<const int4*>(dst + e4);
        atomicAdd(&deg[d.x], 1);
        atomicAdd(&deg[d.y], 1);
        atomicAdd(&deg[d.z], 1);
        atomicAdd(&deg[d.w], 1);
    } else if (e4 < E) {
        for (int k = e4; k < E; ++k) atomicAdd(&deg[dst[k]], 1);
    }
}

// per-block exclusive scan of (deg[i]+1), 1024 elems/block, int4/thread
__global__ __launch_bounds__(256) void block_scan_kernel(
    const int* __restrict__ deg, int* __restrict__ pre, int* __restrict__ blk, int n)
{
    __shared__ int s[256];
    const int t = threadIdx.x;
    const int base = blockIdx.x * 1024 + t * 4;
    int4 d = make_int4(-1, -1, -1, -1);   // +1 -> 0 contribution OOB
    if (base + 3 < n) d = *reinterpret_cast<const int4*>(deg + base);
    else {
        if (base + 0 < n) d.x = deg[base + 0];
        if (base + 1 < n) d.y = deg[base + 1];
        if (base + 2 < n) d.z = deg[base + 2];
        if (base + 3 < n) d.w = deg[base + 3];
    }
    const int v0 = d.x + 1, v1 = d.y + 1, v2 = d.z + 1, v3 = d.w + 1;
    s[t] = v0 + v1 + v2 + v3;
    __syncthreads();
#pragma unroll
    for (int o = 1; o < 256; o <<= 1) {
        int val = 0;
        if (t >= o) val = s[t - o];
        __syncthreads();
        s[t] += val;
        __syncthreads();
    }
    int run = (t == 0) ? 0 : s[t - 1];
    int4 o4;
    o4.x = run; run += v0;
    o4.y = run; run += v1;
    o4.z = run; run += v2;
    o4.w = run; run += v3;
    if (base + 3 < n) *reinterpret_cast<int4*>(pre + base) = o4;
    else {
        if (base + 0 < n) pre[base + 0] = o4.x;
        if (base + 1 < n) pre[base + 1] = o4.y;
        if (base + 2 < n) pre[base + 2] = o4.z;
        if (base + 3 < n) pre[base + 3] = o4.w;
    }
    if (t == 255) blk[blockIdx.x] = s[255];
}

// finalize: block vb adds prefix of block totals (computed in-block via one
// 64-lane reduce over <=64 totals); last block writes csr_off[n].
__global__ __launch_bounds__(256) void finalize_scan_kernel(
    const int* __restrict__ pre, const int* __restrict__ blk,
    int* __restrict__ off, int* __restrict__ cursor, int n, int nvb)
{
    __shared__ int s_add;
    const int vb = blockIdx.x;
    const int t  = threadIdx.x;
    if (t < 64) {
        int v = (t < vb) ? blk[t] : 0;    // nvb <= 64
#pragma unroll
        for (int o = 32; o > 0; o >>= 1) v += __shfl_xor(v, o, 64);
        if (t == 0) s_add = v;
    }
    __syncthreads();
    const int add = s_add;
    const int base = vb * 1024 + t * 4;
    if (base + 3 < n) {
        int4 p = *reinterpret_cast<const int4*>(pre + base);
        p.x += add; p.y += add; p.z += add; p.w += add;
        *reinterpret_cast<int4*>(off + base) = p;
        *reinterpret_cast<int4*>(cursor + base) = p;
    } else {
#pragma unroll
        for (int k = 0; k < 4; ++k)
            if (base + k < n) {
                const int v = pre[base + k] + add;
                off[base + k] = v;
                cursor[base + k] = v;
            }
    }
    if (vb == nvb - 1 && t == 0) off[n] = add + blk[vb];
}

__global__ void scatter_kernel(const int* __restrict__ src, const int* __restrict__ dst,
                               int* __restrict__ cursor, int* __restrict__ csr_src,
                               int E, int N)
{
    const int tid = blockIdx.x * blockDim.x + threadIdx.x;
    const int nq = (E + 3) / 4;
    if (tid < nq) {
        const int e4 = tid * 4;
        if (e4 + 3 < E) {
            const int4 sv = *reinterpret_cast<const int4*>(src + e4);
            const int4 dv = *reinterpret_cast<const int4*>(dst + e4);
            csr_src[atomicAdd(&cursor[dv.x], 1)] = sv.x;
            csr_src[atomicAdd(&cursor[dv.y], 1)] = sv.y;
            csr_src[atomicAdd(&cursor[dv.z], 1)] = sv.z;
            csr_src[atomicAdd(&cursor[dv.w], 1)] = sv.w;
        } else {
            for (int k = e4; k < E; ++k)
                csr_src[atomicAdd(&cursor[dst[k]], 1)] = src[k];
        }
    } else {
        const int nn = tid - nq;
        if (nn < N) csr_src[atomicAdd(&cursor[nn], 1)] = nn;   // self loop
    }
}

// --- pull-based aggregation (R2-proven form) -------------------------------
// out[d,c] = (sum_e w * h[s_e,c]) / (sum_e w) [+bias][relu];  one 64-thread
// block per dst; weights + src idx tiled through LDS.

#define AGG_TILE 64

template <int H, int C, int VPT, bool RELU, typename TOUT>
__global__ __launch_bounds__(H * C / VPT) void aggregate_kernel(
    const int* __restrict__ csr_off,
    const int* __restrict__ csr_src,
    const _Float16* __restrict__ h,  // [N, H*C] fp16
    const float* __restrict__ a_s,   // [N, H]
    const float* __restrict__ a_d,   // [N, H]
    const float* __restrict__ bias,  // [H*C]
    TOUT* __restrict__ out)          // [N, H*C]
{
    const int d   = blockIdx.x;
    const int t   = threadIdx.x;
    const int col = t * VPT;
    const int hh  = col / C;

    __shared__ int   s_src[AGG_TILE];
    __shared__ float s_w[AGG_TILE][H];

    const int beg = csr_off[d];
    const int end = csr_off[d + 1];

    float acc[VPT] = {};
    float wsum = 0.f;

    for (int base = beg; base < end; base += AGG_TILE) {
        const int len = min(AGG_TILE, end - base);
        if (t < len) {
            const int s = csr_src[base + t];
            s_src[t] = s;
#pragma unroll
            for (int h2 = 0; h2 < H; ++h2) {
                float logit = a_s[s * H + h2] + a_d[d * H + h2];
                logit = logit > 0.f ? logit : 0.2f * logit;
                s_w[t][h2] = __expf(logit);
            }
        }
        __syncthreads();
#pragma unroll 4
        for (int j = 0; j < len; ++j) {
            const float w = s_w[j][hh];
            const int   s = s_src[j];
            if constexpr (VPT == 4) {
                half4v hv = *reinterpret_cast<const half4v*>(h + (long)s * (H * C) + col);
                acc[0] += w * (float)hv.x;
                acc[1] += w * (float)hv.y;
                acc[2] += w * (float)hv.z;
                acc[3] += w * (float)hv.w;
            } else {
                half2v hv = *reinterpret_cast<const half2v*>(h + (long)s * (H * C) + col);
                acc[0] += w * (float)hv.x;
                acc[1] += w * (float)hv.y;
            }
            wsum += w;
        }
        __syncthreads();
    }

    const float inv = 1.f / wsum;
    float r[VPT];
#pragma unroll
    for (int k = 0; k < VPT; ++k) {
        r[k] = acc[k] * inv + bias[col + k];
        if (RELU) r[k] = r[k] > 0.f ? r[k] : 0.f;
    }
    if constexpr (__is_same(TOUT, _Float16)) {
#pragma unroll
        for (int k = 0; k < VPT; ++k)
            out[(long)d * (H * C) + col + k] = (_Float16)r[k];
    } else {
#pragma unroll
        for (int k = 0; k < VPT; ++k)
            out[(long)d * (H * C) + col + k] = r[k];
    }
}

// ---------------------------------------------------------------------------

extern "C" void kernel_launch(void* const* d_in, const int* in_sizes, int n_in,
                              void* d_out, int out_size, void* d_ws, size_t ws_size,
                              hipStream_t stream)
{
    const float* x    = (const float*)d_in[0];
    const int*   eidx = (const int*)d_in[1];
    const float* W1   = (const float*)d_in[2];
    const float* as1  = (const float*)d_in[3];
    const float* ad1  = (const float*)d_in[4];
    const float* b1   = (const float*)d_in[5];
    const float* W2   = (const float*)d_in[6];
    const float* as2  = (const float*)d_in[7];
    const float* ad2  = (const float*)d_in[8];
    const float* b2   = (const float*)d_in[9];
    float* out = (float*)d_out;

    const int IN_FEATS = 256;
    const int N = in_sizes[0] / IN_FEATS;    // 50000
    const int E = in_sizes[1] / 2;           // 800000

    const int* esrc = eidx;
    const int* edst = eidx + E;

    size_t off = 0;
    auto alloc = [&](size_t bytes) -> void* {
        void* p = (char*)d_ws + off;
        off += (bytes + 255) & ~(size_t)255;
        return p;
    };
    _Float16* h1h   = (_Float16*)alloc((size_t)N * 256 * 2);
    _Float16* o1h   = (_Float16*)alloc((size_t)N * 256 * 2);
    _Float16* h2h   = (_Float16*)alloc((size_t)N * 128 * 2);
    float* a1s      = (float*)alloc((size_t)N * 2 * 4);
    float* a1d      = (float*)alloc((size_t)N * 2 * 4);
    float* a2s      = (float*)alloc((size_t)N * 4);
    float* a2d      = (float*)alloc((size_t)N * 4);
    int*   deg      = (int*)alloc((size_t)N * 4);
    int*   pre      = (int*)alloc((size_t)N * 4);
    int*   cursor   = (int*)alloc((size_t)N * 4);
    int*   csr_off  = (int*)alloc((size_t)(N + 1) * 4);
    int*   csr_src  = (int*)alloc((size_t)(E + N) * 4);
    int*   blk      = (int*)alloc(64 * 4);

    const int nvb = (N + 1023) / 1024;    // 49 <= 64

    // --- CSR build (5 dispatches, all wide grids) ---
    hipMemsetAsync(deg, 0, (size_t)N * 4, stream);
    count_kernel<<<((E + 3) / 4 + 255) / 256, 256, 0, stream>>>(edst, deg, E);
    block_scan_kernel<<<nvb, 256, 0, stream>>>(deg, pre, blk, N);
    finalize_scan_kernel<<<nvb, 256, 0, stream>>>(pre, blk, csr_off, cursor, N, nvb);
    {
        const int nThr = (E + 3) / 4 + N;
        scatter_kernel<<<(nThr + 255) / 256, 256, 0, stream>>>(
            esrc, edst, cursor, csr_src, E, N);
    }

    // --- layer 1: GEMM + fused att logits, then aggregate ---
    {
        dim3 grid((N + 127) / 128, 2);
        gemm_att_kernel<float, 2><<<grid, 256, 0, stream>>>(
            x, W1, h1h, as1, ad1, a1s, a1d, N, 256);
    }
    aggregate_kernel<2, 128, 4, true, _Float16><<<N, 64, 0, stream>>>(
        csr_off, csr_src, h1h, a1s, a1d, b1, o1h);

    // --- layer 2: GEMM + fused att logits, then aggregate ---
    {
        dim3 grid((N + 127) / 128, 1);
        gemm_att_kernel<_Float16, 1><<<grid, 256, 0, stream>>>(
            o1h, W2, h2h, as2, ad2, a2s, a2d, N, 256);
    }
    aggregate_kernel<1, 128, 2, false, float><<<N, 64, 0, stream>>>(
        csr_off, csr_src, h2h, a2s, a2d, b2, out);
}

// Round 7
// 323.734 us; speedup vs baseline: 1.4874x; 1.0438x over previous
//
#include <hip/hip_runtime.h>
#include <hip/hip_bf16.h>

// ---------------------------------------------------------------------------
// GAT 2-layer forward on MI355X (gfx950).
// R6: scatter fused into gemm1 as a latency-hidden prologue (standalone
//     scatter was 61us of pure atomic round-trip latency, 0.24% VALU —
//     perfect fusion donor into the MFMA-busy GEMM). Self-loops pre-placed
//     by finalize (cursor starts at csr_off+1). 8 dispatches.
// fp16 intermediates, MFMA f16 GEMMs + fused att-logit epilogue, softmax
// shift-invariance (no max pass), end-normalization (no denom pass).
// ---------------------------------------------------------------------------

typedef _Float16 half8v __attribute__((ext_vector_type(8)));
typedef _Float16 half4v __attribute__((ext_vector_type(4)));
typedef _Float16 half2v __attribute__((ext_vector_type(2)));
typedef float f32x4 __attribute__((ext_vector_type(4)));

// --- MFMA GEMM + fused attention logits (+ optional fused edge scatter) ----
// C[M, H*128](f16) = A[M,K] @ B[H*128, K]^T ; a_s/a_d from fp32 accumulators.
// 128x128 tile, BK=32, 4 waves; grid.y = head. SCATTER: blocks first issue a
// grid-stride scatter of edges into csr_src (atomic cursor alloc) — the
// atomic latency hides under other waves' MFMA work.

template <typename TA, int H, bool SCATTER>
__global__ __launch_bounds__(256) void gemm_att_kernel(
    const TA* __restrict__ A,        // [M,K] row-major (float or _Float16)
    const float* __restrict__ B,     // [H*128, K] row-major fp32 weights
    _Float16* __restrict__ C,        // [M, H*128] fp16 out
    const float* __restrict__ att_s, // [H*128]
    const float* __restrict__ att_d, // [H*128]
    float* __restrict__ a_s,         // [M*H]
    float* __restrict__ a_d,         // [M*H]
    int M, int K,
    const int* __restrict__ esrc, const int* __restrict__ edst,
    int* __restrict__ cursor, int* __restrict__ csr_src, int E)
{
    constexpr int BM = 128, BK = 32, LDA = 40;   // 40 f16 = 80 B = 5*16 B
    constexpr int NCOL = H * 128;
    __shared__ _Float16 Ah[BM * LDA];
    __shared__ _Float16 Bh[BM * LDA];
    __shared__ float red[2][2][64][2];           // [wm][wn][row][s|d]

    const int tid = threadIdx.x;

    // ---- fused scatter prologue (layer-1 only) ----
    if constexpr (SCATTER) {
        const int nq   = (E + 3) >> 2;
        const int nblk = gridDim.x * gridDim.y;
        const int bid  = blockIdx.y * gridDim.x + blockIdx.x;
        for (int q = bid * 256 + tid; q < nq; q += nblk * 256) {
            const int e4 = q * 4;
            if (e4 + 3 < E) {
                const int4 sv = *reinterpret_cast<const int4*>(esrc + e4);
                const int4 dv = *reinterpret_cast<const int4*>(edst + e4);
                csr_src[atomicAdd(&cursor[dv.x], 1)] = sv.x;
                csr_src[atomicAdd(&cursor[dv.y], 1)] = sv.y;
                csr_src[atomicAdd(&cursor[dv.z], 1)] = sv.z;
                csr_src[atomicAdd(&cursor[dv.w], 1)] = sv.w;
            } else {
                for (int k = e4; k < E; ++k)
                    csr_src[atomicAdd(&cursor[edst[k]], 1)] = esrc[k];
            }
        }
    }

    const int m0 = blockIdx.x * BM;
    const int by = blockIdx.y;                   // head
    const int n0 = by * 128;
    const int w  = tid >> 6;
    const int l  = tid & 63;
    const int wm = (w >> 1) * 64;
    const int wn = (w & 1) * 64;
    const int lr = l & 15;
    const int lq = l >> 4;

    f32x4 acc[4][4] = {};

    for (int k0 = 0; k0 < K; k0 += BK) {
        if constexpr (__is_same(TA, float)) {
#pragma unroll
            for (int it = 0; it < 4; ++it) {
                const int row = (tid >> 3) + it * 32;
                const int gm  = min(m0 + row, M - 1);
                const int c4  = (tid & 7) * 4;
                float4 v = *reinterpret_cast<const float4*>(A + (long)gm * K + k0 + c4);
                half4v o = { (_Float16)v.x, (_Float16)v.y, (_Float16)v.z, (_Float16)v.w };
                *reinterpret_cast<half4v*>(&Ah[row * LDA + c4]) = o;
            }
        } else {
#pragma unroll
            for (int it = 0; it < 2; ++it) {
                const int row = (tid >> 2) + it * 64;
                const int gm  = min(m0 + row, M - 1);
                const int c8  = (tid & 3) * 8;
                float4 v = *reinterpret_cast<const float4*>((const char*)A + ((long)gm * K + k0 + c8) * 2);
                *reinterpret_cast<float4*>(&Ah[row * LDA + c8]) = v;
            }
        }
#pragma unroll
        for (int it = 0; it < 4; ++it) {
            const int row = (tid >> 3) + it * 32;
            const int c4  = (tid & 7) * 4;
            float4 v = *reinterpret_cast<const float4*>(B + (long)(n0 + row) * K + k0 + c4);
            half4v o = { (_Float16)v.x, (_Float16)v.y, (_Float16)v.z, (_Float16)v.w };
            *reinterpret_cast<half4v*>(&Bh[row * LDA + c4]) = o;
        }
        __syncthreads();

        half8v af[4], bf[4];
#pragma unroll
        for (int i = 0; i < 4; ++i)
            af[i] = *reinterpret_cast<const half8v*>(&Ah[(wm + i * 16 + lr) * LDA + lq * 8]);
#pragma unroll
        for (int j = 0; j < 4; ++j)
            bf[j] = *reinterpret_cast<const half8v*>(&Bh[(wn + j * 16 + lr) * LDA + lq * 8]);
#pragma unroll
        for (int i = 0; i < 4; ++i)
#pragma unroll
            for (int j = 0; j < 4; ++j)
                acc[i][j] = __builtin_amdgcn_mfma_f32_16x16x32_f16(af[i], bf[j], acc[i][j], 0, 0, 0);
        __syncthreads();
    }

    // ---- store C ----
#pragma unroll
    for (int i = 0; i < 4; ++i) {
        const int gm_base = m0 + wm + i * 16 + lq * 4;
#pragma unroll
        for (int r = 0; r < 4; ++r) {
            const int gm = gm_base + r;
            if (gm < M) {
#pragma unroll
                for (int j = 0; j < 4; ++j)
                    C[(long)gm * NCOL + n0 + wn + j * 16 + lr] = (_Float16)acc[i][j][r];
            }
        }
    }

    // ---- fused attention logits ----
    float asv[4], adv[4];
#pragma unroll
    for (int j = 0; j < 4; ++j) {
        asv[j] = att_s[n0 + wn + j * 16 + lr];
        adv[j] = att_d[n0 + wn + j * 16 + lr];
    }
    float ps[4][4] = {}, pd[4][4] = {};
#pragma unroll
    for (int i = 0; i < 4; ++i)
#pragma unroll
        for (int j = 0; j < 4; ++j)
#pragma unroll
            for (int r = 0; r < 4; ++r) {
                ps[i][r] += acc[i][j][r] * asv[j];
                pd[i][r] += acc[i][j][r] * adv[j];
            }
#pragma unroll
    for (int o = 1; o < 16; o <<= 1)
#pragma unroll
        for (int i = 0; i < 4; ++i)
#pragma unroll
            for (int r = 0; r < 4; ++r) {
                ps[i][r] += __shfl_xor(ps[i][r], o, 64);
                pd[i][r] += __shfl_xor(pd[i][r], o, 64);
            }
    if (lr == 0) {
#pragma unroll
        for (int i = 0; i < 4; ++i)
#pragma unroll
            for (int r = 0; r < 4; ++r) {
                const int row = i * 16 + lq * 4 + r;
                red[wm >> 6][wn >> 6][row][0] = ps[i][r];
                red[wm >> 6][wn >> 6][row][1] = pd[i][r];
            }
    }
    __syncthreads();
    if (wn == 0) {                       // waves 0 and 2 cover wm = 0, 64
        const int row = l;
        const int gm = m0 + wm + row;
        if (gm < M) {
            const int wi = wm >> 6;
            a_s[(long)gm * H + by] = red[wi][0][row][0] + red[wi][1][row][0];
            a_d[(long)gm * H + by] = red[wi][0][row][1] + red[wi][1][row][1];
        }
    }
}

// --- CSR build --------------------------------------------------------------

__global__ void count_kernel(const int* __restrict__ dst, int* __restrict__ deg, int E)
{
    const int tid = blockIdx.x * blockDim.x + threadIdx.x;
    const int e4 = tid * 4;
    if (e4 + 3 < E) {
        const int4 d = *reinterpret_cast<const int4*>(dst + e4);
        atomicAdd(&deg[d.x], 1);
        atomicAdd(&deg[d.y], 1);
        atomicAdd(&deg[d.z], 1);
        atomicAdd(&deg[d.w], 1);
    } else if (e4 < E) {
        for (int k = e4; k < E; ++k) atomicAdd(&deg[dst[k]], 1);
    }
}

// per-block exclusive scan of (deg[i]+1), 1024 elems/block, int4/thread
__global__ __launch_bounds__(256) void block_scan_kernel(
    const int* __restrict__ deg, int* __restrict__ pre, int* __restrict__ blk, int n)
{
    __shared__ int s[256];
    const int t = threadIdx.x;
    const int base = blockIdx.x * 1024 + t * 4;
    int4 d = make_int4(-1, -1, -1, -1);   // +1 -> 0 contribution OOB
    if (base + 3 < n) d = *reinterpret_cast<const int4*>(deg + base);
    else {
        if (base + 0 < n) d.x = deg[base + 0];
        if (base + 1 < n) d.y = deg[base + 1];
        if (base + 2 < n) d.z = deg[base + 2];
        if (base + 3 < n) d.w = deg[base + 3];
    }
    const int v0 = d.x + 1, v1 = d.y + 1, v2 = d.z + 1, v3 = d.w + 1;
    s[t] = v0 + v1 + v2 + v3;
    __syncthreads();
#pragma unroll
    for (int o = 1; o < 256; o <<= 1) {
        int val = 0;
        if (t >= o) val = s[t - o];
        __syncthreads();
        s[t] += val;
        __syncthreads();
    }
    int run = (t == 0) ? 0 : s[t - 1];
    int4 o4;
    o4.x = run; run += v0;
    o4.y = run; run += v1;
    o4.z = run; run += v2;
    o4.w = run; run += v3;
    if (base + 3 < n) *reinterpret_cast<int4*>(pre + base) = o4;
    else {
        if (base + 0 < n) pre[base + 0] = o4.x;
        if (base + 1 < n) pre[base + 1] = o4.y;
        if (base + 2 < n) pre[base + 2] = o4.z;
        if (base + 3 < n) pre[base + 3] = o4.w;
    }
    if (t == 255) blk[blockIdx.x] = s[255];
}

// finalize: add prefix of block totals; emit csr_off; pre-place self-loop at
// row start (csr_src[off] = node) and start cursor at off+1.
__global__ __launch_bounds__(256) void finalize_scan_kernel(
    const int* __restrict__ pre, const int* __restrict__ blk,
    int* __restrict__ off, int* __restrict__ cursor, int* __restrict__ csr_src,
    int n, int nvb)
{
    __shared__ int s_add;
    const int vb = blockIdx.x;
    const int t  = threadIdx.x;
    if (t < 64) {
        int v = (t < vb) ? blk[t] : 0;    // nvb <= 64
#pragma unroll
        for (int o = 32; o > 0; o >>= 1) v += __shfl_xor(v, o, 64);
        if (t == 0) s_add = v;
    }
    __syncthreads();
    const int add = s_add;
    const int base = vb * 1024 + t * 4;
    if (base + 3 < n) {
        int4 p = *reinterpret_cast<const int4*>(pre + base);
        p.x += add; p.y += add; p.z += add; p.w += add;
        *reinterpret_cast<int4*>(off + base) = p;
        int4 c = make_int4(p.x + 1, p.y + 1, p.z + 1, p.w + 1);
        *reinterpret_cast<int4*>(cursor + base) = c;
        csr_src[p.x] = base + 0;
        csr_src[p.y] = base + 1;
        csr_src[p.z] = base + 2;
        csr_src[p.w] = base + 3;
    } else {
#pragma unroll
        for (int k = 0; k < 4; ++k)
            if (base + k < n) {
                const int v = pre[base + k] + add;
                off[base + k] = v;
                cursor[base + k] = v + 1;
                csr_src[v] = base + k;
            }
    }
    if (vb == nvb - 1 && t == 0) off[n] = add + blk[vb];
}

// --- pull-based aggregation (R2-proven form) -------------------------------

#define AGG_TILE 64

template <int H, int C, int VPT, bool RELU, typename TOUT>
__global__ __launch_bounds__(H * C / VPT) void aggregate_kernel(
    const int* __restrict__ csr_off,
    const int* __restrict__ csr_src,
    const _Float16* __restrict__ h,  // [N, H*C] fp16
    const float* __restrict__ a_s,   // [N, H]
    const float* __restrict__ a_d,   // [N, H]
    const float* __restrict__ bias,  // [H*C]
    TOUT* __restrict__ out)          // [N, H*C]
{
    const int d   = blockIdx.x;
    const int t   = threadIdx.x;
    const int col = t * VPT;
    const int hh  = col / C;

    __shared__ int   s_src[AGG_TILE];
    __shared__ float s_w[AGG_TILE][H];

    const int beg = csr_off[d];
    const int end = csr_off[d + 1];

    float acc[VPT] = {};
    float wsum = 0.f;

    for (int base = beg; base < end; base += AGG_TILE) {
        const int len = min(AGG_TILE, end - base);
        if (t < len) {
            const int s = csr_src[base + t];
            s_src[t] = s;
#pragma unroll
            for (int h2 = 0; h2 < H; ++h2) {
                float logit = a_s[s * H + h2] + a_d[d * H + h2];
                logit = logit > 0.f ? logit : 0.2f * logit;
                s_w[t][h2] = __expf(logit);
            }
        }
        __syncthreads();
#pragma unroll 4
        for (int j = 0; j < len; ++j) {
            const float w = s_w[j][hh];
            const int   s = s_src[j];
            if constexpr (VPT == 4) {
                half4v hv = *reinterpret_cast<const half4v*>(h + (long)s * (H * C) + col);
                acc[0] += w * (float)hv.x;
                acc[1] += w * (float)hv.y;
                acc[2] += w * (float)hv.z;
                acc[3] += w * (float)hv.w;
            } else {
                half2v hv = *reinterpret_cast<const half2v*>(h + (long)s * (H * C) + col);
                acc[0] += w * (float)hv.x;
                acc[1] += w * (float)hv.y;
            }
            wsum += w;
        }
        __syncthreads();
    }

    const float inv = 1.f / wsum;
    float r[VPT];
#pragma unroll
    for (int k = 0; k < VPT; ++k) {
        r[k] = acc[k] * inv + bias[col + k];
        if (RELU) r[k] = r[k] > 0.f ? r[k] : 0.f;
    }
    if constexpr (__is_same(TOUT, _Float16)) {
#pragma unroll
        for (int k = 0; k < VPT; ++k)
            out[(long)d * (H * C) + col + k] = (_Float16)r[k];
    } else {
#pragma unroll
        for (int k = 0; k < VPT; ++k)
            out[(long)d * (H * C) + col + k] = r[k];
    }
}

// ---------------------------------------------------------------------------

extern "C" void kernel_launch(void* const* d_in, const int* in_sizes, int n_in,
                              void* d_out, int out_size, void* d_ws, size_t ws_size,
                              hipStream_t stream)
{
    const float* x    = (const float*)d_in[0];
    const int*   eidx = (const int*)d_in[1];
    const float* W1   = (const float*)d_in[2];
    const float* as1  = (const float*)d_in[3];
    const float* ad1  = (const float*)d_in[4];
    const float* b1   = (const float*)d_in[5];
    const float* W2   = (const float*)d_in[6];
    const float* as2  = (const float*)d_in[7];
    const float* ad2  = (const float*)d_in[8];
    const float* b2   = (const float*)d_in[9];
    float* out = (float*)d_out;

    const int IN_FEATS = 256;
    const int N = in_sizes[0] / IN_FEATS;    // 50000
    const int E = in_sizes[1] / 2;           // 800000

    const int* esrc = eidx;
    const int* edst = eidx + E;

    size_t off = 0;
    auto alloc = [&](size_t bytes) -> void* {
        void* p = (char*)d_ws + off;
        off += (bytes + 255) & ~(size_t)255;
        return p;
    };
    _Float16* h1h   = (_Float16*)alloc((size_t)N * 256 * 2);
    _Float16* o1h   = (_Float16*)alloc((size_t)N * 256 * 2);
    _Float16* h2h   = (_Float16*)alloc((size_t)N * 128 * 2);
    float* a1s      = (float*)alloc((size_t)N * 2 * 4);
    float* a1d      = (float*)alloc((size_t)N * 2 * 4);
    float* a2s      = (float*)alloc((size_t)N * 4);
    float* a2d      = (float*)alloc((size_t)N * 4);
    int*   deg      = (int*)alloc((size_t)N * 4);
    int*   pre      = (int*)alloc((size_t)N * 4);
    int*   cursor   = (int*)alloc((size_t)N * 4);
    int*   csr_off  = (int*)alloc((size_t)(N + 1) * 4);
    int*   csr_src  = (int*)alloc((size_t)(E + N) * 4);
    int*   blk      = (int*)alloc(64 * 4);

    const int nvb = (N + 1023) / 1024;    // 49 <= 64

    // --- CSR offsets (4 dispatches; scatter fused into gemm1) ---
    hipMemsetAsync(deg, 0, (size_t)N * 4, stream);
    count_kernel<<<((E + 3) / 4 + 255) / 256, 256, 0, stream>>>(edst, deg, E);
    block_scan_kernel<<<nvb, 256, 0, stream>>>(deg, pre, blk, N);
    finalize_scan_kernel<<<nvb, 256, 0, stream>>>(pre, blk, csr_off, cursor, csr_src, N, nvb);

    // --- layer 1: GEMM + att logits + fused edge scatter, then aggregate ---
    {
        dim3 grid((N + 127) / 128, 2);
        gemm_att_kernel<float, 2, true><<<grid, 256, 0, stream>>>(
            x, W1, h1h, as1, ad1, a1s, a1d, N, 256,
            esrc, edst, cursor, csr_src, E);
    }
    aggregate_kernel<2, 128, 4, true, _Float16><<<N, 64, 0, stream>>>(
        csr_off, csr_src, h1h, a1s, a1d, b1, o1h);

    // --- layer 2: GEMM + att logits, then aggregate ---
    {
        dim3 grid((N + 127) / 128, 1);
        gemm_att_kernel<_Float16, 1, false><<<grid, 256, 0, stream>>>(
            o1h, W2, h2h, as2, ad2, a2s, a2d, N, 256,
            nullptr, nullptr, nullptr, nullptr, 0);
    }
    aggregate_kernel<1, 128, 2, false, float><<<N, 64, 0, stream>>>(
        csr_off, csr_src, h2h, a2s, a2d, b2, out);
}

// Round 8
// 291.154 us; speedup vs baseline: 1.6538x; 1.1119x over previous
//
#include <hip/hip_runtime.h>
#include <hip/hip_bf16.h>

// ---------------------------------------------------------------------------
// GAT 2-layer forward on MI355X (gfx950).
// R7: (a) rank trick — count_kernel stores the atomicAdd return value as the
//         edge's within-dst rank; scatter becomes atomic-free:
//         csr_src[off[dst]+1+rank] = src (fire-and-forget store).
//     (b) block-specialized fusion — gemm1 grid = 784 GEMM blocks + 192
//         dedicated scatter blocks, all co-resident (104 VGPR -> 4 blk/CU),
//         so scatter truly overlaps MFMA (R6's uniform prologue just
//         phase-serialized). cursor array deleted.
// fp16 intermediates, MFMA f16 GEMMs + fused att-logit epilogue, softmax
// shift-invariance (no max pass), end-normalization (no denom pass).
// ---------------------------------------------------------------------------

typedef _Float16 half8v __attribute__((ext_vector_type(8)));
typedef _Float16 half4v __attribute__((ext_vector_type(4)));
typedef _Float16 half2v __attribute__((ext_vector_type(2)));
typedef float f32x4 __attribute__((ext_vector_type(4)));

// --- MFMA GEMM + fused attention logits (+ block-specialized scatter) ------
// GEMM blocks: C[M, H*128](f16) = A[M,K] @ B[H*128,K]^T; a_s/a_d from fp32
// accumulators in the epilogue. 128x128 tile, BK=32, 4 waves.
// Scatter blocks (bid >= GB*H): atomic-free CSR scatter via precomputed rank.
// 1D grid; bid < GB*H: m0=(bid%GB)*128, head=bid/GB.

template <typename TA, int H, bool SCATTER>
__global__ __launch_bounds__(256) void gemm_att_kernel(
    const TA* __restrict__ A,        // [M,K] row-major (float or _Float16)
    const float* __restrict__ B,     // [H*128, K] row-major fp32 weights
    _Float16* __restrict__ C,        // [M, H*128] fp16 out
    const float* __restrict__ att_s, // [H*128]
    const float* __restrict__ att_d, // [H*128]
    float* __restrict__ a_s,         // [M*H]
    float* __restrict__ a_d,         // [M*H]
    int M, int K, int GB,            // GB = GEMM blocks per head
    const int* __restrict__ esrc, const int* __restrict__ edst,
    const int* __restrict__ rank, const int* __restrict__ csr_off,
    int* __restrict__ csr_src, int E, int nScatBlk)
{
    constexpr int BM = 128, BK = 32, LDA = 40;   // 40 f16 = 80 B = 5*16 B
    constexpr int NCOL = H * 128;
    __shared__ _Float16 Ah[BM * LDA];
    __shared__ _Float16 Bh[BM * LDA];
    __shared__ float red[2][2][64][2];           // [wm][wn][row][s|d]

    const int tid = threadIdx.x;
    const int bid = blockIdx.x;

    if constexpr (SCATTER) {
        if (bid >= GB * H) {
            // ---- dedicated scatter block: no atomics, no dependencies ----
            const int sbid = bid - GB * H;
            const int nq = (E + 3) >> 2;
            for (int q = sbid * 256 + tid; q < nq; q += nScatBlk * 256) {
                const int e4 = q * 4;
                if (e4 + 3 < E) {
                    const int4 sv = *reinterpret_cast<const int4*>(esrc + e4);
                    const int4 dv = *reinterpret_cast<const int4*>(edst + e4);
                    const int4 rv = *reinterpret_cast<const int4*>(rank + e4);
                    csr_src[csr_off[dv.x] + 1 + rv.x] = sv.x;
                    csr_src[csr_off[dv.y] + 1 + rv.y] = sv.y;
                    csr_src[csr_off[dv.z] + 1 + rv.z] = sv.z;
                    csr_src[csr_off[dv.w] + 1 + rv.w] = sv.w;
                } else {
                    for (int k = e4; k < E; ++k)
                        csr_src[csr_off[edst[k]] + 1 + rank[k]] = esrc[k];
                }
            }
            return;
        }
    }

    const int m0 = (bid % GB) * BM;
    const int by = bid / GB;                     // head
    const int n0 = by * 128;
    const int w  = tid >> 6;
    const int l  = tid & 63;
    const int wm = (w >> 1) * 64;
    const int wn = (w & 1) * 64;
    const int lr = l & 15;
    const int lq = l >> 4;

    f32x4 acc[4][4] = {};

    for (int k0 = 0; k0 < K; k0 += BK) {
        if constexpr (__is_same(TA, float)) {
#pragma unroll
            for (int it = 0; it < 4; ++it) {
                const int row = (tid >> 3) + it * 32;
                const int gm  = min(m0 + row, M - 1);
                const int c4  = (tid & 7) * 4;
                float4 v = *reinterpret_cast<const float4*>(A + (long)gm * K + k0 + c4);
                half4v o = { (_Float16)v.x, (_Float16)v.y, (_Float16)v.z, (_Float16)v.w };
                *reinterpret_cast<half4v*>(&Ah[row * LDA + c4]) = o;
            }
        } else {
#pragma unroll
            for (int it = 0; it < 2; ++it) {
                const int row = (tid >> 2) + it * 64;
                const int gm  = min(m0 + row, M - 1);
                const int c8  = (tid & 3) * 8;
                float4 v = *reinterpret_cast<const float4*>((const char*)A + ((long)gm * K + k0 + c8) * 2);
                *reinterpret_cast<float4*>(&Ah[row * LDA + c8]) = v;
            }
        }
#pragma unroll
        for (int it = 0; it < 4; ++it) {
            const int row = (tid >> 3) + it * 32;
            const int c4  = (tid & 7) * 4;
            float4 v = *reinterpret_cast<const float4*>(B + (long)(n0 + row) * K + k0 + c4);
            half4v o = { (_Float16)v.x, (_Float16)v.y, (_Float16)v.z, (_Float16)v.w };
            *reinterpret_cast<half4v*>(&Bh[row * LDA + c4]) = o;
        }
        __syncthreads();

        half8v af[4], bf[4];
#pragma unroll
        for (int i = 0; i < 4; ++i)
            af[i] = *reinterpret_cast<const half8v*>(&Ah[(wm + i * 16 + lr) * LDA + lq * 8]);
#pragma unroll
        for (int j = 0; j < 4; ++j)
            bf[j] = *reinterpret_cast<const half8v*>(&Bh[(wn + j * 16 + lr) * LDA + lq * 8]);
#pragma unroll
        for (int i = 0; i < 4; ++i)
#pragma unroll
            for (int j = 0; j < 4; ++j)
                acc[i][j] = __builtin_amdgcn_mfma_f32_16x16x32_f16(af[i], bf[j], acc[i][j], 0, 0, 0);
        __syncthreads();
    }

    // ---- store C ----
#pragma unroll
    for (int i = 0; i < 4; ++i) {
        const int gm_base = m0 + wm + i * 16 + lq * 4;
#pragma unroll
        for (int r = 0; r < 4; ++r) {
            const int gm = gm_base + r;
            if (gm < M) {
#pragma unroll
                for (int j = 0; j < 4; ++j)
                    C[(long)gm * NCOL + n0 + wn + j * 16 + lr] = (_Float16)acc[i][j][r];
            }
        }
    }

    // ---- fused attention logits ----
    float asv[4], adv[4];
#pragma unroll
    for (int j = 0; j < 4; ++j) {
        asv[j] = att_s[n0 + wn + j * 16 + lr];
        adv[j] = att_d[n0 + wn + j * 16 + lr];
    }
    float ps[4][4] = {}, pd[4][4] = {};
#pragma unroll
    for (int i = 0; i < 4; ++i)
#pragma unroll
        for (int j = 0; j < 4; ++j)
#pragma unroll
            for (int r = 0; r < 4; ++r) {
                ps[i][r] += acc[i][j][r] * asv[j];
                pd[i][r] += acc[i][j][r] * adv[j];
            }
#pragma unroll
    for (int o = 1; o < 16; o <<= 1)
#pragma unroll
        for (int i = 0; i < 4; ++i)
#pragma unroll
            for (int r = 0; r < 4; ++r) {
                ps[i][r] += __shfl_xor(ps[i][r], o, 64);
                pd[i][r] += __shfl_xor(pd[i][r], o, 64);
            }
    if (lr == 0) {
#pragma unroll
        for (int i = 0; i < 4; ++i)
#pragma unroll
            for (int r = 0; r < 4; ++r) {
                const int row = i * 16 + lq * 4 + r;
                red[wm >> 6][wn >> 6][row][0] = ps[i][r];
                red[wm >> 6][wn >> 6][row][1] = pd[i][r];
            }
    }
    __syncthreads();
    if (wn == 0) {                       // waves 0 and 2 cover wm = 0, 64
        const int row = l;
        const int gm = m0 + wm + row;
        if (gm < M) {
            const int wi = wm >> 6;
            a_s[(long)gm * H + by] = red[wi][0][row][0] + red[wi][1][row][0];
            a_d[(long)gm * H + by] = red[wi][0][row][1] + red[wi][1][row][1];
        }
    }
}

// --- CSR build --------------------------------------------------------------

// count + rank: rank[e] = position of edge e within its dst's neighborhood
__global__ void count_kernel(const int* __restrict__ dst, int* __restrict__ deg,
                             int* __restrict__ rank, int E)
{
    const int tid = blockIdx.x * blockDim.x + threadIdx.x;
    const int e4 = tid * 4;
    if (e4 + 3 < E) {
        const int4 d = *reinterpret_cast<const int4*>(dst + e4);
        int4 r;
        r.x = atomicAdd(&deg[d.x], 1);
        r.y = atomicAdd(&deg[d.y], 1);
        r.z = atomicAdd(&deg[d.z], 1);
        r.w = atomicAdd(&deg[d.w], 1);
        *reinterpret_cast<int4*>(rank + e4) = r;
    } else if (e4 < E) {
        for (int k = e4; k < E; ++k) rank[k] = atomicAdd(&deg[dst[k]], 1);
    }
}

// per-block exclusive scan of (deg[i]+1), 1024 elems/block, int4/thread
__global__ __launch_bounds__(256) void block_scan_kernel(
    const int* __restrict__ deg, int* __restrict__ pre, int* __restrict__ blk, int n)
{
    __shared__ int s[256];
    const int t = threadIdx.x;
    const int base = blockIdx.x * 1024 + t * 4;
    int4 d = make_int4(-1, -1, -1, -1);   // +1 -> 0 contribution OOB
    if (base + 3 < n) d = *reinterpret_cast<const int4*>(deg + base);
    else {
        if (base + 0 < n) d.x = deg[base + 0];
        if (base + 1 < n) d.y = deg[base + 1];
        if (base + 2 < n) d.z = deg[base + 2];
        if (base + 3 < n) d.w = deg[base + 3];
    }
    const int v0 = d.x + 1, v1 = d.y + 1, v2 = d.z + 1, v3 = d.w + 1;
    s[t] = v0 + v1 + v2 + v3;
    __syncthreads();
#pragma unroll
    for (int o = 1; o < 256; o <<= 1) {
        int val = 0;
        if (t >= o) val = s[t - o];
        __syncthreads();
        s[t] += val;
        __syncthreads();
    }
    int run = (t == 0) ? 0 : s[t - 1];
    int4 o4;
    o4.x = run; run += v0;
    o4.y = run; run += v1;
    o4.z = run; run += v2;
    o4.w = run; run += v3;
    if (base + 3 < n) *reinterpret_cast<int4*>(pre + base) = o4;
    else {
        if (base + 0 < n) pre[base + 0] = o4.x;
        if (base + 1 < n) pre[base + 1] = o4.y;
        if (base + 2 < n) pre[base + 2] = o4.z;
        if (base + 3 < n) pre[base + 3] = o4.w;
    }
    if (t == 255) blk[blockIdx.x] = s[255];
}

// finalize: add prefix of block totals; emit csr_off; pre-place self-loop at
// row start (csr_src[off] = node).
__global__ __launch_bounds__(256) void finalize_scan_kernel(
    const int* __restrict__ pre, const int* __restrict__ blk,
    int* __restrict__ off, int* __restrict__ csr_src, int n, int nvb)
{
    __shared__ int s_add;
    const int vb = blockIdx.x;
    const int t  = threadIdx.x;
    if (t < 64) {
        int v = (t < vb) ? blk[t] : 0;    // nvb <= 64
#pragma unroll
        for (int o = 32; o > 0; o >>= 1) v += __shfl_xor(v, o, 64);
        if (t == 0) s_add = v;
    }
    __syncthreads();
    const int add = s_add;
    const int base = vb * 1024 + t * 4;
    if (base + 3 < n) {
        int4 p = *reinterpret_cast<const int4*>(pre + base);
        p.x += add; p.y += add; p.z += add; p.w += add;
        *reinterpret_cast<int4*>(off + base) = p;
        csr_src[p.x] = base + 0;
        csr_src[p.y] = base + 1;
        csr_src[p.z] = base + 2;
        csr_src[p.w] = base + 3;
    } else {
#pragma unroll
        for (int k = 0; k < 4; ++k)
            if (base + k < n) {
                const int v = pre[base + k] + add;
                off[base + k] = v;
                csr_src[v] = base + k;
            }
    }
    if (vb == nvb - 1 && t == 0) off[n] = add + blk[vb];
}

// --- pull-based aggregation (R2-proven form) -------------------------------

#define AGG_TILE 64

template <int H, int C, int VPT, bool RELU, typename TOUT>
__global__ __launch_bounds__(H * C / VPT) void aggregate_kernel(
    const int* __restrict__ csr_off,
    const int* __restrict__ csr_src,
    const _Float16* __restrict__ h,  // [N, H*C] fp16
    const float* __restrict__ a_s,   // [N, H]
    const float* __restrict__ a_d,   // [N, H]
    const float* __restrict__ bias,  // [H*C]
    TOUT* __restrict__ out)          // [N, H*C]
{
    const int d   = blockIdx.x;
    const int t   = threadIdx.x;
    const int col = t * VPT;
    const int hh  = col / C;

    __shared__ int   s_src[AGG_TILE];
    __shared__ float s_w[AGG_TILE][H];

    const int beg = csr_off[d];
    const int end = csr_off[d + 1];

    float acc[VPT] = {};
    float wsum = 0.f;

    for (int base = beg; base < end; base += AGG_TILE) {
        const int len = min(AGG_TILE, end - base);
        if (t < len) {
            const int s = csr_src[base + t];
            s_src[t] = s;
#pragma unroll
            for (int h2 = 0; h2 < H; ++h2) {
                float logit = a_s[s * H + h2] + a_d[d * H + h2];
                logit = logit > 0.f ? logit : 0.2f * logit;
                s_w[t][h2] = __expf(logit);
            }
        }
        __syncthreads();
#pragma unroll 4
        for (int j = 0; j < len; ++j) {
            const float w = s_w[j][hh];
            const int   s = s_src[j];
            if constexpr (VPT == 4) {
                half4v hv = *reinterpret_cast<const half4v*>(h + (long)s * (H * C) + col);
                acc[0] += w * (float)hv.x;
                acc[1] += w * (float)hv.y;
                acc[2] += w * (float)hv.z;
                acc[3] += w * (float)hv.w;
            } else {
                half2v hv = *reinterpret_cast<const half2v*>(h + (long)s * (H * C) + col);
                acc[0] += w * (float)hv.x;
                acc[1] += w * (float)hv.y;
            }
            wsum += w;
        }
        __syncthreads();
    }

    const float inv = 1.f / wsum;
    float r[VPT];
#pragma unroll
    for (int k = 0; k < VPT; ++k) {
        r[k] = acc[k] * inv + bias[col + k];
        if (RELU) r[k] = r[k] > 0.f ? r[k] : 0.f;
    }
    if constexpr (__is_same(TOUT, _Float16)) {
#pragma unroll
        for (int k = 0; k < VPT; ++k)
            out[(long)d * (H * C) + col + k] = (_Float16)r[k];
    } else {
#pragma unroll
        for (int k = 0; k < VPT; ++k)
            out[(long)d * (H * C) + col + k] = r[k];
    }
}

// ---------------------------------------------------------------------------

extern "C" void kernel_launch(void* const* d_in, const int* in_sizes, int n_in,
                              void* d_out, int out_size, void* d_ws, size_t ws_size,
                              hipStream_t stream)
{
    const float* x    = (const float*)d_in[0];
    const int*   eidx = (const int*)d_in[1];
    const float* W1   = (const float*)d_in[2];
    const float* as1  = (const float*)d_in[3];
    const float* ad1  = (const float*)d_in[4];
    const float* b1   = (const float*)d_in[5];
    const float* W2   = (const float*)d_in[6];
    const float* as2  = (const float*)d_in[7];
    const float* ad2  = (const float*)d_in[8];
    const float* b2   = (const float*)d_in[9];
    float* out = (float*)d_out;

    const int IN_FEATS = 256;
    const int N = in_sizes[0] / IN_FEATS;    // 50000
    const int E = in_sizes[1] / 2;           // 800000

    const int* esrc = eidx;
    const int* edst = eidx + E;

    size_t off = 0;
    auto alloc = [&](size_t bytes) -> void* {
        void* p = (char*)d_ws + off;
        off += (bytes + 255) & ~(size_t)255;
        return p;
    };
    _Float16* h1h   = (_Float16*)alloc((size_t)N * 256 * 2);
    _Float16* o1h   = (_Float16*)alloc((size_t)N * 256 * 2);
    _Float16* h2h   = (_Float16*)alloc((size_t)N * 128 * 2);
    float* a1s      = (float*)alloc((size_t)N * 2 * 4);
    float* a1d      = (float*)alloc((size_t)N * 2 * 4);
    float* a2s      = (float*)alloc((size_t)N * 4);
    float* a2d      = (float*)alloc((size_t)N * 4);
    int*   deg      = (int*)alloc((size_t)N * 4);
    int*   pre      = (int*)alloc((size_t)N * 4);
    int*   rank     = (int*)alloc((size_t)E * 4);
    int*   csr_off  = (int*)alloc((size_t)(N + 1) * 4);
    int*   csr_src  = (int*)alloc((size_t)(E + N) * 4);
    int*   blk      = (int*)alloc(64 * 4);

    const int nvb = (N + 1023) / 1024;    // 49 <= 64

    // --- CSR offsets + ranks (scatter itself fused into gemm1) ---
    hipMemsetAsync(deg, 0, (size_t)N * 4, stream);
    count_kernel<<<((E + 3) / 4 + 255) / 256, 256, 0, stream>>>(edst, deg, rank, E);
    block_scan_kernel<<<nvb, 256, 0, stream>>>(deg, pre, blk, N);
    finalize_scan_kernel<<<nvb, 256, 0, stream>>>(pre, blk, csr_off, csr_src, N, nvb);

    // --- layer 1: GEMM(784 blocks) + dedicated scatter blocks(192) ---
    {
        const int GB = (N + 127) / 128;      // 392
        const int nScat = 192;               // 784 + 192 = 976 <= 1024 co-res
        gemm_att_kernel<float, 2, true><<<GB * 2 + nScat, 256, 0, stream>>>(
            x, W1, h1h, as1, ad1, a1s, a1d, N, 256, GB,
            esrc, edst, rank, csr_off, csr_src, E, nScat);
    }
    aggregate_kernel<2, 128, 4, true, _Float16><<<N, 64, 0, stream>>>(
        csr_off, csr_src, h1h, a1s, a1d, b1, o1h);

    // --- layer 2: GEMM + att logits, then aggregate ---
    {
        const int GB = (N + 127) / 128;
        gemm_att_kernel<_Float16, 1, false><<<GB, 256, 0, stream>>>(
            o1h, W2, h2h, as2, ad2, a2s, a2d, N, 256, GB,
            nullptr, nullptr, nullptr, nullptr, nullptr, 0, 0);
    }
    aggregate_kernel<1, 128, 2, false, float><<<N, 64, 0, stream>>>(
        csr_off, csr_src, h2h, a2s, a2d, b2, out);
}